// Round 8
// baseline (690.914 us; speedup 1.0000x reference)
//
#include <hip/hip_runtime.h>
#include <hip/hip_bf16.h>

// GCN 4-layer, linear network => collapse to:
// out = A^4 x0 * c4 + A^3 1 * c3 + A^2 1 * c2 + A 1 * c1 + b4,
// A = D^-1/2 (Adj+I) D^-1/2. Propagate in scaled space u' = D^-1 (Adj+I) u,
// epilogue multiplies sqrt(deg). Channels (x-path, ones-path) packed float2.
// Dtypes (R1-R4 verified): read_length int32, edge_index int32, W/b fp32, out fp32.
//
// R8: (a) csr_build dropped — gathers are bucket-local LDS accumulation with
// strided coalesced epart loads + manual 4x unroll (R7 post-mortem: gather is
// TA/L1-lookup-bound ~13us/pass floor; CSR row loop's lane imbalance was the
// overhead, sorting unnecessary for LDS-side accumulation); (b) scatter PB
// 512->256 so each block's per-bucket run ~15 edges ~ 1 line and the per-XCD
// active-line set fits 4MB L2 -> stores can merge before eviction (R6/R7:
// WRITE_SIZE 210MB = 26B/store write-through, occupancy fix was neutral =>
// merge failure, not latency, is the scatter limiter).

#define BLK  256
#define SBLK 1024         // scatter/count block
#define NB   2048         // buckets
#define BSH  8            // bucket = dst >> 8  (256 nodes / bucket)
#define PB   256          // partition blocks (runs ~1 line, L2-mergeable)

// If rl were int64 (values in [0,20000)), every odd int32 word is 0.
__global__ void probe_i64(const int* __restrict__ rl32, int* __restrict__ flag) {
    int acc = 0;
    for (int k = threadIdx.x; k < 1024; k += blockDim.x)
        acc |= rl32[2 * k + 1];
    if (acc != 0) atomicOr(flag, 1);   // 1 => int32 layout
}

__global__ __launch_bounds__(SBLK)
void bucket_count(const int* __restrict__ dst, int* __restrict__ table, int E) {
    __shared__ int h[NB];
    int j = blockIdx.x, t = threadIdx.x;
    for (int b = t; b < NB; b += SBLK) h[b] = 0;
    __syncthreads();
    int chunk = (E + PB - 1) / PB;
    int beg = j * chunk, end = min(beg + chunk, E);
    for (int e = beg + t; e < end; e += SBLK)
        atomicAdd(&h[((unsigned)dst[e]) >> BSH], 1);
    __syncthreads();
    for (int b = t; b < NB; b += SBLK) table[j * NB + b] = h[b];   // coalesced
}

__global__ void bucket_tot(const int* __restrict__ table, int* __restrict__ tot) {
    int b = blockIdx.x * blockDim.x + threadIdx.x;   // NB threads
    int s = 0;
    for (int j = 0; j < PB; ++j) s += table[j * NB + b];  // coalesced rows
    tot[b] = s;
}

__global__ void scan_base(const int* __restrict__ tot, int* __restrict__ base) {
    __shared__ int sm[BLK];
    int t = threadIdx.x;
    int loc[NB / BLK]; int s = 0;
#pragma unroll
    for (int k = 0; k < NB / BLK; ++k) { loc[k] = tot[t * (NB / BLK) + k]; s += loc[k]; }
    sm[t] = s; __syncthreads();
    int v = s;
    for (int off = 1; off < BLK; off <<= 1) {
        int add = (t >= off) ? sm[t - off] : 0;
        __syncthreads(); sm[t] += add; __syncthreads();
    }
    int run = sm[t] - v;   // exclusive across threads
#pragma unroll
    for (int k = 0; k < NB / BLK; ++k) { base[t * (NB / BLK) + k] = run; run += loc[k]; }
    if (t == BLK - 1) base[NB] = run;   // == E
}

// in-place: table[j][b] := bucket_base[b] + sum_{j'<j} table[j'][b]
__global__ void scan_table(int* __restrict__ table, const int* __restrict__ base) {
    int b = blockIdx.x * blockDim.x + threadIdx.x;
    int run = base[b];
    for (int j = 0; j < PB; ++j) {       // coalesced read+write per j
        int v = table[j * NB + b];
        table[j * NB + b] = run;
        run += v;
    }
}

__global__ __launch_bounds__(SBLK)
void scatter(const int* __restrict__ src, const int* __restrict__ dst,
             const int* __restrict__ table, unsigned* __restrict__ epart, int E) {
    __shared__ int cur[NB];
    int j = blockIdx.x, t = threadIdx.x;
    for (int b = t; b < NB; b += SBLK) cur[b] = table[j * NB + b];
    __syncthreads();
    int chunk = (E + PB - 1) / PB;
    int beg = j * chunk, end = min(beg + chunk, E);
    for (int e = beg + t; e < end; e += SBLK) {
        unsigned d = (unsigned)dst[e];
        int slot = atomicAdd(&cur[d >> BSH], 1);          // LDS cursor
        epart[slot] = ((d & 255u) << 19) | (unsigned)src[e];
    }
}

// per-bucket degree + node init (deg = in-count + 1 self-loop)
__global__ void bucket_init(const unsigned* __restrict__ epart, const int* __restrict__ base,
                            const int* __restrict__ rl, const int* __restrict__ flag,
                            float* __restrict__ dinv, float2* __restrict__ v0, int N) {
    __shared__ int cnt[256];
    int b = blockIdx.x, t = threadIdx.x;
    cnt[t] = 0;
    __syncthreads();
    int beg = base[b], end = base[b + 1];
    for (int e = beg + t; e < end; e += BLK)
        atomicAdd(&cnt[epart[e] >> 19], 1);
    __syncthreads();
    int node = b * 256 + t;
    if (node < N) {
        int v = (*flag) ? rl[node] : rl[2 * node];
        float d = (float)cnt[t] + 1.0f;
        dinv[node] = 1.0f / d;
        float rs = rsqrtf(d);
        float2 u; u.x = rs * ((float)v * (1.0f / 20000.0f)); u.y = rs;
        v0[node] = u;
    }
}

__global__ void coeffs(const float* __restrict__ W1, const float* __restrict__ b1,
                       const float* __restrict__ W2, const float* __restrict__ b2,
                       const float* __restrict__ W3, const float* __restrict__ b3,
                       const float* __restrict__ W4, const float* __restrict__ b4,
                       float* __restrict__ c) {
    __shared__ float p3[16], q3[16], r3[16];
    int t = threadIdx.x;
    if (t == 0) {
        float p2[8], q2[8];
        for (int j = 0; j < 8; ++j) {
            float s1 = 0.f, s2 = 0.f;
            for (int k = 0; k < 4; ++k) {
                float w = W2[k * 8 + j];
                s1 += W1[k] * w;
                s2 += b1[k] * w;
            }
            p2[j] = s1; q2[j] = s2;
        }
        for (int m = 0; m < 16; ++m) {
            float s1 = 0.f, s2 = 0.f, s3 = 0.f;
            for (int j = 0; j < 8; ++j) {
                float w = W3[j * 16 + m];
                s1 += p2[j] * w; s2 += q2[j] * w;
                s3 += b2[j] * w;
            }
            p3[m] = s1; q3[m] = s2; r3[m] = s3;
        }
    }
    __syncthreads();
    if (t < 32) {
        float c4 = 0.f, c3 = 0.f, c2 = 0.f, c1 = 0.f;
        for (int k = 0; k < 16; ++k) {
            float w = W4[k * 32 + t];
            c4 += p3[k] * w; c3 += q3[k] * w; c2 += r3[k] * w;
            c1 += b3[k] * w;
        }
        c[t] = c4; c[32 + t] = c3; c[64 + t] = c2; c[96 + t] = c1;
    }
}

// one sweep: block per bucket, strided coalesced epart loads, 4x unrolled
// (4 loads -> 4 gathers -> 8 ds_add_f32, all independent), LDS accumulate.
__global__ void gather_pass(const unsigned* __restrict__ ep, const int* __restrict__ base,
                            const float2* __restrict__ vin, float2* __restrict__ vout,
                            const float* __restrict__ dinv, float* __restrict__ zsave, int N) {
    __shared__ float accA[256], accB[256];
    int b = blockIdx.x, t = threadIdx.x;
    accA[t] = 0.f; accB[t] = 0.f;
    __syncthreads();
    int beg = base[b], end = base[b + 1];
    int e = beg + t;
    for (; e + 3 * BLK < end; e += 4 * BLK) {
        unsigned p0 = ep[e];
        unsigned p1 = ep[e + BLK];
        unsigned p2 = ep[e + 2 * BLK];
        unsigned p3 = ep[e + 3 * BLK];
        float2 u0 = vin[p0 & 0x7FFFFu];
        float2 u1 = vin[p1 & 0x7FFFFu];
        float2 u2 = vin[p2 & 0x7FFFFu];
        float2 u3 = vin[p3 & 0x7FFFFu];
        atomicAdd(&accA[p0 >> 19], u0.x); atomicAdd(&accB[p0 >> 19], u0.y);
        atomicAdd(&accA[p1 >> 19], u1.x); atomicAdd(&accB[p1 >> 19], u1.y);
        atomicAdd(&accA[p2 >> 19], u2.x); atomicAdd(&accB[p2 >> 19], u2.y);
        atomicAdd(&accA[p3 >> 19], u3.x); atomicAdd(&accB[p3 >> 19], u3.y);
    }
    for (; e < end; e += BLK) {
        unsigned p = ep[e];
        float2 u = vin[p & 0x7FFFFu];
        atomicAdd(&accA[p >> 19], u.x); atomicAdd(&accB[p >> 19], u.y);
    }
    __syncthreads();
    int node = b * 256 + t;
    if (node < N) {
        float2 self = vin[node];
        float di = dinv[node];
        float2 o; o.x = (accA[t] + self.x) * di; o.y = (accB[t] + self.y) * di;
        vout[node] = o;
        if (zsave) zsave[node] = o.y;
    }
}

__global__ void write_out(const float2* __restrict__ v0, const float* __restrict__ z1,
                          const float* __restrict__ z2, const float* __restrict__ z3,
                          const float* __restrict__ dinv, const float* __restrict__ c,
                          const float* __restrict__ b4,
                          float* __restrict__ out, int N) {
    int t = blockIdx.x * blockDim.x + threadIdx.x;
    int i = t >> 5, f = t & 31;
    if (i < N) {
        float sq = rsqrtf(dinv[i]);  // = sqrt(deg)
        float v = sq * (v0[i].x * c[f] + z3[i] * c[32 + f] + z2[i] * c[64 + f]
                        + z1[i] * c[96 + f])
                  + b4[f];
        out[(size_t)i * 32 + f] = v;
    }
}

extern "C" void kernel_launch(void* const* d_in, const int* in_sizes, int n_in,
                              void* d_out, int out_size, void* d_ws, size_t ws_size,
                              hipStream_t stream) {
    const int N = in_sizes[0];
    const int E = in_sizes[1] / 2;
    const int* rl  = (const int*)d_in[0];
    const int* src = (const int*)d_in[1];
    const int* dst = src + E;
    const float* W1 = (const float*)d_in[2];
    const float* b1 = (const float*)d_in[3];
    const float* W2 = (const float*)d_in[4];
    const float* b2 = (const float*)d_in[5];
    const float* W3 = (const float*)d_in[6];
    const float* b3 = (const float*)d_in[7];
    const float* W4 = (const float*)d_in[8];
    const float* b4 = (const float*)d_in[9];

    // workspace (~18.3 MB)
    float*  dinv = (float*)d_ws;              // N
    float2* v0   = (float2*)(dinv + N);       // 2N floats
    float2* v1   = v0 + N;                    // 2N floats
    float*  z1   = (float*)(v1 + N);          // N
    float*  z2   = z1 + N;                    // N
    float*  z3   = z2 + N;                    // N
    int*    table = (int*)(z3 + N);           // PB*NB ints (2 MB)
    int*    btot  = table + PB * NB;          // NB
    int*    bbase = btot + NB;                // NB+1
    float*  c     = (float*)(bbase + NB + 1); // 128
    int*    flag  = (int*)(c + 128);          // 1

    // packed partitioned edges live in d_out (scratch until write_out)
    unsigned* epart = (unsigned*)d_out;       // E uint32 (32 MB of 64 MB)

    const int gbNode = (N + 255) / 256;       // 1954 buckets containing nodes

    hipMemsetAsync(flag, 0, sizeof(int), stream);
    probe_i64<<<1, BLK, 0, stream>>>(rl, flag);

    // radix partition by dst bucket — zero global atomics
    bucket_count<<<PB, SBLK, 0, stream>>>(dst, table, E);
    bucket_tot<<<NB / BLK, BLK, 0, stream>>>(table, btot);
    scan_base<<<1, BLK, 0, stream>>>(btot, bbase);
    scan_table<<<NB / BLK, BLK, 0, stream>>>(table, bbase);
    scatter<<<PB, SBLK, 0, stream>>>(src, dst, table, epart, E);

    bucket_init<<<gbNode, BLK, 0, stream>>>(epart, bbase, rl, flag, dinv, v0, N);
    coeffs<<<1, 64, 0, stream>>>(W1, b1, W2, b2, W3, b3, W4, b4, c);

    // 4 propagation sweeps, ping-pong v0<->v1
    gather_pass<<<gbNode, BLK, 0, stream>>>(epart, bbase, v0, v1, dinv, z1, N);
    gather_pass<<<gbNode, BLK, 0, stream>>>(epart, bbase, v1, v0, dinv, z2, N);
    gather_pass<<<gbNode, BLK, 0, stream>>>(epart, bbase, v0, v1, dinv, z3, N);
    gather_pass<<<gbNode, BLK, 0, stream>>>(epart, bbase, v1, v0, dinv, (float*)nullptr, N);

    write_out<<<(N * 32 + BLK - 1) / BLK, BLK, 0, stream>>>(
        v0, z1, z2, z3, dinv, c, b4, (float*)d_out, N);
}

// Round 9
// 642.131 us; speedup vs baseline: 1.0760x; 1.0760x over previous
//
#include <hip/hip_runtime.h>
#include <hip/hip_bf16.h>

// GCN 4-layer, linear network => collapse to:
// out = A^4 x0 * c4 + A^3 1 * c3 + A^2 1 * c2 + A 1 * c1 + b4,
// A = D^-1/2 (Adj+I) D^-1/2. Propagate in scaled space u' = D^-1 (Adj+I) u,
// epilogue multiplies sqrt(deg). Dtypes (R1-R4 verified): read_length int32,
// edge_index int32, W/b fp32, out fp32.
//
// R9: (a) propagated node pair stored as packed bf16x2 (4B/node, 2MB total):
// R5-R8 gathers were stuck at ~90-130us/pass because the 4MB fp32 float2
// array = one whole XCD L2 and the epart stream thrashed it -> HBM sector
// refetch. 2MB fits alongside the stream; accumulation stays fp32 in LDS,
// z-saves taken pre-rounding in fp32. (b) NB 2048->512: per-XCD open store
// lines = 32 blocks x NB = 16K <= 64K L2 lines (R7/R8 had exactly 64K ->
// partial lines evicted before merging; PB changes never touched this
// product). Runs now ~61 edges ~ 4 full lines -> stores merge.

#define BLK  256
#define SBLK 1024         // scatter/count/gather block
#define NB   512          // buckets
#define BSH  10           // bucket = dst >> 10  (1024 nodes / bucket)
#define PB   256          // partition blocks

// ---- manual bf16 pack/unpack (RNE), no API dependency
__device__ __forceinline__ unsigned f2bf(float f) {
    unsigned u = __float_as_uint(f);
    return (u + 0x7FFFu + ((u >> 16) & 1u)) >> 16;
}
__device__ __forceinline__ float bf2f(unsigned h) {
    return __uint_as_float(h << 16);
}
__device__ __forceinline__ unsigned packbf2(float x, float y) {
    return (f2bf(y) << 16) | f2bf(x);
}

// If rl were int64 (values in [0,20000)), every odd int32 word is 0.
__global__ void probe_i64(const int* __restrict__ rl32, int* __restrict__ flag) {
    int acc = 0;
    for (int k = threadIdx.x; k < 1024; k += blockDim.x)
        acc |= rl32[2 * k + 1];
    if (acc != 0) atomicOr(flag, 1);   // 1 => int32 layout
}

__global__ __launch_bounds__(SBLK)
void bucket_count(const int* __restrict__ dst, int* __restrict__ table, int E) {
    __shared__ int h[NB];
    int j = blockIdx.x, t = threadIdx.x;
    for (int b = t; b < NB; b += SBLK) h[b] = 0;
    __syncthreads();
    int chunk = (E + PB - 1) / PB;
    int beg = j * chunk, end = min(beg + chunk, E);
    for (int e = beg + t; e < end; e += SBLK)
        atomicAdd(&h[((unsigned)dst[e]) >> BSH], 1);
    __syncthreads();
    for (int b = t; b < NB; b += SBLK) table[j * NB + b] = h[b];   // coalesced
}

__global__ void bucket_tot(const int* __restrict__ table, int* __restrict__ tot) {
    int b = blockIdx.x * blockDim.x + threadIdx.x;   // NB threads
    if (b >= NB) return;
    int s = 0;
    for (int j = 0; j < PB; ++j) s += table[j * NB + b];  // coalesced rows
    tot[b] = s;
}

__global__ void scan_base(const int* __restrict__ tot, int* __restrict__ base) {
    __shared__ int sm[BLK];
    int t = threadIdx.x;
    int loc[NB / BLK]; int s = 0;
#pragma unroll
    for (int k = 0; k < NB / BLK; ++k) { loc[k] = tot[t * (NB / BLK) + k]; s += loc[k]; }
    sm[t] = s; __syncthreads();
    int v = s;
    for (int off = 1; off < BLK; off <<= 1) {
        int add = (t >= off) ? sm[t - off] : 0;
        __syncthreads(); sm[t] += add; __syncthreads();
    }
    int run = sm[t] - v;   // exclusive across threads
#pragma unroll
    for (int k = 0; k < NB / BLK; ++k) { base[t * (NB / BLK) + k] = run; run += loc[k]; }
    if (t == BLK - 1) base[NB] = run;   // == E
}

// in-place: table[j][b] := bucket_base[b] + sum_{j'<j} table[j'][b]
__global__ void scan_table(int* __restrict__ table, const int* __restrict__ base) {
    int b = blockIdx.x * blockDim.x + threadIdx.x;
    if (b >= NB) return;
    int run = base[b];
    for (int j = 0; j < PB; ++j) {       // coalesced read+write per j
        int v = table[j * NB + b];
        table[j * NB + b] = run;
        run += v;
    }
}

__global__ __launch_bounds__(SBLK)
void scatter(const int* __restrict__ src, const int* __restrict__ dst,
             const int* __restrict__ table, unsigned* __restrict__ epart, int E) {
    __shared__ int cur[NB];
    int j = blockIdx.x, t = threadIdx.x;
    for (int b = t; b < NB; b += SBLK) cur[b] = table[j * NB + b];
    __syncthreads();
    int chunk = (E + PB - 1) / PB;
    int beg = j * chunk, end = min(beg + chunk, E);
    for (int e = beg + t; e < end; e += SBLK) {
        unsigned d = (unsigned)dst[e];
        int slot = atomicAdd(&cur[d >> BSH], 1);          // LDS cursor
        epart[slot] = ((d & 1023u) << 19) | (unsigned)src[e];  // 29 bits
    }
}

// per-bucket degree + node init (deg = in-count + 1 self-loop)
__global__ __launch_bounds__(SBLK)
void bucket_init(const unsigned* __restrict__ epart, const int* __restrict__ base,
                 const int* __restrict__ rl, const int* __restrict__ flag,
                 float* __restrict__ dinv, unsigned* __restrict__ v0, int N) {
    __shared__ int cnt[1024];
    int b = blockIdx.x, t = threadIdx.x;
    cnt[t] = 0;
    __syncthreads();
    int beg = base[b], end = base[b + 1];
    for (int e = beg + t; e < end; e += SBLK)
        atomicAdd(&cnt[epart[e] >> 19], 1);
    __syncthreads();
    int node = b * 1024 + t;
    if (node < N) {
        int v = (*flag) ? rl[node] : rl[2 * node];
        float d = (float)cnt[t] + 1.0f;
        dinv[node] = 1.0f / d;
        float rs = rsqrtf(d);
        v0[node] = packbf2(rs * ((float)v * (1.0f / 20000.0f)), rs);
    }
}

__global__ void coeffs(const float* __restrict__ W1, const float* __restrict__ b1,
                       const float* __restrict__ W2, const float* __restrict__ b2,
                       const float* __restrict__ W3, const float* __restrict__ b3,
                       const float* __restrict__ W4, const float* __restrict__ b4,
                       float* __restrict__ c) {
    __shared__ float p3[16], q3[16], r3[16];
    int t = threadIdx.x;
    if (t == 0) {
        float p2[8], q2[8];
        for (int j = 0; j < 8; ++j) {
            float s1 = 0.f, s2 = 0.f;
            for (int k = 0; k < 4; ++k) {
                float w = W2[k * 8 + j];
                s1 += W1[k] * w;
                s2 += b1[k] * w;
            }
            p2[j] = s1; q2[j] = s2;
        }
        for (int m = 0; m < 16; ++m) {
            float s1 = 0.f, s2 = 0.f, s3 = 0.f;
            for (int j = 0; j < 8; ++j) {
                float w = W3[j * 16 + m];
                s1 += p2[j] * w; s2 += q2[j] * w;
                s3 += b2[j] * w;
            }
            p3[m] = s1; q3[m] = s2; r3[m] = s3;
        }
    }
    __syncthreads();
    if (t < 32) {
        float c4 = 0.f, c3 = 0.f, c2 = 0.f, c1 = 0.f;
        for (int k = 0; k < 16; ++k) {
            float w = W4[k * 32 + t];
            c4 += p3[k] * w; c3 += q3[k] * w; c2 += r3[k] * w;
            c1 += b3[k] * w;
        }
        c[t] = c4; c[32 + t] = c3; c[64 + t] = c2; c[96 + t] = c1;
    }
}

// one sweep: block per bucket (1024 nodes), bf16x2 gathers (2MB working set),
// fp32 LDS accumulation, coalesced stores; z-save in fp32 pre-rounding.
__global__ __launch_bounds__(SBLK)
void gather_pass(const unsigned* __restrict__ ep, const int* __restrict__ base,
                 const unsigned* __restrict__ vin, unsigned* __restrict__ vout,
                 const float* __restrict__ dinv, float* __restrict__ zsave, int N) {
    __shared__ float accA[1024], accB[1024];
    int b = blockIdx.x, t = threadIdx.x;
    accA[t] = 0.f; accB[t] = 0.f;
    __syncthreads();
    int beg = base[b], end = base[b + 1];
    int e = beg + t;
    for (; e + 3 * SBLK < end; e += 4 * SBLK) {
        unsigned p0 = ep[e];
        unsigned p1 = ep[e + SBLK];
        unsigned p2 = ep[e + 2 * SBLK];
        unsigned p3 = ep[e + 3 * SBLK];
        unsigned u0 = vin[p0 & 0x7FFFFu];
        unsigned u1 = vin[p1 & 0x7FFFFu];
        unsigned u2 = vin[p2 & 0x7FFFFu];
        unsigned u3 = vin[p3 & 0x7FFFFu];
        atomicAdd(&accA[p0 >> 19], bf2f(u0 & 0xFFFFu)); atomicAdd(&accB[p0 >> 19], bf2f(u0 >> 16));
        atomicAdd(&accA[p1 >> 19], bf2f(u1 & 0xFFFFu)); atomicAdd(&accB[p1 >> 19], bf2f(u1 >> 16));
        atomicAdd(&accA[p2 >> 19], bf2f(u2 & 0xFFFFu)); atomicAdd(&accB[p2 >> 19], bf2f(u2 >> 16));
        atomicAdd(&accA[p3 >> 19], bf2f(u3 & 0xFFFFu)); atomicAdd(&accB[p3 >> 19], bf2f(u3 >> 16));
    }
    for (; e < end; e += SBLK) {
        unsigned p = ep[e];
        unsigned u = vin[p & 0x7FFFFu];
        atomicAdd(&accA[p >> 19], bf2f(u & 0xFFFFu)); atomicAdd(&accB[p >> 19], bf2f(u >> 16));
    }
    __syncthreads();
    int node = b * 1024 + t;
    if (node < N) {
        unsigned self = vin[node];
        float di = dinv[node];
        float ox = (accA[t] + bf2f(self & 0xFFFFu)) * di;
        float oy = (accB[t] + bf2f(self >> 16)) * di;
        vout[node] = packbf2(ox, oy);
        if (zsave) zsave[node] = oy;     // fp32, pre-rounding
    }
}

__global__ void write_out(const unsigned* __restrict__ vfin, const float* __restrict__ z1,
                          const float* __restrict__ z2, const float* __restrict__ z3,
                          const float* __restrict__ dinv, const float* __restrict__ c,
                          const float* __restrict__ b4,
                          float* __restrict__ out, int N) {
    int t = blockIdx.x * blockDim.x + threadIdx.x;
    int i = t >> 5, f = t & 31;
    if (i < N) {
        float sq = rsqrtf(dinv[i]);  // = sqrt(deg)
        float vx = bf2f(vfin[i] & 0xFFFFu);
        float v = sq * (vx * c[f] + z3[i] * c[32 + f] + z2[i] * c[64 + f]
                        + z1[i] * c[96 + f])
                  + b4[f];
        out[(size_t)i * 32 + f] = v;
    }
}

extern "C" void kernel_launch(void* const* d_in, const int* in_sizes, int n_in,
                              void* d_out, int out_size, void* d_ws, size_t ws_size,
                              hipStream_t stream) {
    const int N = in_sizes[0];
    const int E = in_sizes[1] / 2;
    const int* rl  = (const int*)d_in[0];
    const int* src = (const int*)d_in[1];
    const int* dst = src + E;
    const float* W1 = (const float*)d_in[2];
    const float* b1 = (const float*)d_in[3];
    const float* W2 = (const float*)d_in[4];
    const float* b2 = (const float*)d_in[5];
    const float* W3 = (const float*)d_in[6];
    const float* b3 = (const float*)d_in[7];
    const float* W4 = (const float*)d_in[8];
    const float* b4 = (const float*)d_in[9];

    // workspace (~15 MB)
    float*    dinv = (float*)d_ws;               // N
    unsigned* v0   = (unsigned*)(dinv + N);      // N (packed bf16x2)
    unsigned* v1   = v0 + N;                     // N
    float*    z1   = (float*)(v1 + N);           // N
    float*    z2   = z1 + N;                     // N
    float*    z3   = z2 + N;                     // N
    int*      table = (int*)(z3 + N);            // PB*NB ints (512 KB)
    int*      btot  = table + PB * NB;           // NB
    int*      bbase = btot + NB;                 // NB+1
    float*    c     = (float*)(bbase + NB + 1);  // 128
    int*      flag  = (int*)(c + 128);           // 1

    // packed partitioned edges live in d_out (scratch until write_out)
    unsigned* epart = (unsigned*)d_out;          // E uint32 (32 MB of 64 MB)

    const int gbB = (N + 1023) / 1024;           // buckets containing nodes (489)

    hipMemsetAsync(flag, 0, sizeof(int), stream);
    probe_i64<<<1, BLK, 0, stream>>>(rl, flag);

    // radix partition by dst bucket — zero global atomics
    bucket_count<<<PB, SBLK, 0, stream>>>(dst, table, E);
    bucket_tot<<<(NB + BLK - 1) / BLK, BLK, 0, stream>>>(table, btot);
    scan_base<<<1, BLK, 0, stream>>>(btot, bbase);
    scan_table<<<(NB + BLK - 1) / BLK, BLK, 0, stream>>>(table, bbase);
    scatter<<<PB, SBLK, 0, stream>>>(src, dst, table, epart, E);

    bucket_init<<<gbB, SBLK, 0, stream>>>(epart, bbase, rl, flag, dinv, v0, N);
    coeffs<<<1, 64, 0, stream>>>(W1, b1, W2, b2, W3, b3, W4, b4, c);

    // 4 propagation sweeps, ping-pong v0<->v1
    gather_pass<<<gbB, SBLK, 0, stream>>>(epart, bbase, v0, v1, dinv, z1, N);
    gather_pass<<<gbB, SBLK, 0, stream>>>(epart, bbase, v1, v0, dinv, z2, N);
    gather_pass<<<gbB, SBLK, 0, stream>>>(epart, bbase, v0, v1, dinv, z3, N);
    gather_pass<<<gbB, SBLK, 0, stream>>>(epart, bbase, v1, v0, dinv, (float*)nullptr, N);

    write_out<<<(N * 32 + BLK - 1) / BLK, BLK, 0, stream>>>(
        v0, z1, z2, z3, dinv, c, b4, (float*)d_out, N);
}